// Round 1
// baseline (2444.059 us; speedup 1.0000x reference)
//
#include <hip/hip_runtime.h>
#include <stdint.h>

// SequenceTagger: BiLSTM-CRF
//   T=128, B=32, E=4096, H=512, K=20, START=18, STOP=19, NEG=-1e4
// Pipeline:
//   1. cvt fp32->bf16: x, W_e2n, W_hh_f/b
//   2. GEMM1: x' = x @ W_e2n^T + b_e2n          (bf16 out)
//   3. cvt W_ih_f/b (reuse W_e2n buffer)
//   4. GEMM2: xg = x' @ [W_ih_f;W_ih_b]^T + b   (bf16 out, reuse x buffer)
//   5. 128x lstm_step (both dirs, MFMA, c fp32, h bf16 double-buffered)
//   6. feats GEMV  7. CRF forward + score

#define NEGV (-10000.0f)

typedef __bf16          bf16x8 __attribute__((ext_vector_type(8)));
typedef float           f32x4  __attribute__((ext_vector_type(4)));
typedef unsigned short  u16x8  __attribute__((ext_vector_type(8)));

typedef const __attribute__((address_space(1))) unsigned int* as1p;
typedef __attribute__((address_space(3))) unsigned int* as3p;

__device__ __forceinline__ void lds_cp16(const void* g, void* l) {
  __builtin_amdgcn_global_load_lds((as1p)g, (as3p)l, 16, 0, 0);
}

__device__ __forceinline__ unsigned short f2bf(float f) {
  unsigned int u = __float_as_uint(f);
  u += 0x7fffu + ((u >> 16) & 1u);   // RNE truncate to bf16
  return (unsigned short)(u >> 16);
}
__device__ __forceinline__ float bf2f(unsigned short h) {
  return __uint_as_float(((unsigned int)h) << 16);
}

// ---------------- fp32 -> bf16 (x4 vectorized) ----------------
__global__ __launch_bounds__(256) void cvt_f32_bf16(const float* __restrict__ in,
                                                    unsigned short* __restrict__ out,
                                                    int n4) {
  int stride = gridDim.x * blockDim.x;
  for (int i = blockIdx.x * blockDim.x + threadIdx.x; i < n4; i += stride) {
    float4 f = ((const float4*)in)[i];
    ushort4 o;
    o.x = f2bf(f.x); o.y = f2bf(f.y); o.z = f2bf(f.z); o.w = f2bf(f.w);
    ((ushort4*)out)[i] = o;
  }
}

// ---------------- bf16 GEMM: C[m,n] = sum_k A[m,k]*B[n,k] + bias(n) ----------------
// 128x128 tile, BK=32, 4 waves (2x2), each wave 64x64 via 4x4 MFMA 16x16x32.
// M,N multiples of 128; K multiple of 32. C is bf16.
__global__ __launch_bounds__(256) void gemm_bf16(const unsigned short* __restrict__ A,
                                                 const unsigned short* __restrict__ B,
                                                 unsigned short* __restrict__ C,
                                                 const float* __restrict__ bias0,
                                                 const float* __restrict__ bias1,
                                                 int nsplit, int M, int N, int K) {
  __shared__ unsigned short As[128 * 32];
  __shared__ unsigned short Bs[128 * 32];
  const int tid   = threadIdx.x;
  const int lane  = tid & 63;
  const int wm    = (tid >> 6) >> 1;
  const int wn    = (tid >> 6) & 1;
  const int nb    = N >> 7;
  const int bm    = (int)(blockIdx.x / nb) << 7;
  const int bn    = (int)(blockIdx.x % nb) << 7;
  const int srow  = tid >> 2;         // 0..63 staging row
  const int skoff = (tid & 3) * 8;    // 8-elem chunk in 32-elem row
  const int lrow  = lane & 15;
  const int lk    = (lane >> 4) * 8;

  f32x4 acc[4][4];
#pragma unroll
  for (int i = 0; i < 4; ++i)
#pragma unroll
    for (int j = 0; j < 4; ++j) acc[i][j] = (f32x4){0.f, 0.f, 0.f, 0.f};

  for (int k0 = 0; k0 < K; k0 += 32) {
    lds_cp16(A + (size_t)(bm + srow) * K + k0 + skoff,      &As[tid * 8]);
    lds_cp16(A + (size_t)(bm + 64 + srow) * K + k0 + skoff, &As[2048 + tid * 8]);
    lds_cp16(B + (size_t)(bn + srow) * K + k0 + skoff,      &Bs[tid * 8]);
    lds_cp16(B + (size_t)(bn + 64 + srow) * K + k0 + skoff, &Bs[2048 + tid * 8]);
    __syncthreads();   // compiler emits vmcnt(0) drain before s_barrier
    bf16x8 af[4], bfr[4];
#pragma unroll
    for (int mi = 0; mi < 4; ++mi)
      af[mi] = *(const bf16x8*)&As[(wm * 64 + mi * 16 + lrow) * 32 + lk];
#pragma unroll
    for (int ni = 0; ni < 4; ++ni)
      bfr[ni] = *(const bf16x8*)&Bs[(wn * 64 + ni * 16 + lrow) * 32 + lk];
#pragma unroll
    for (int mi = 0; mi < 4; ++mi)
#pragma unroll
      for (int ni = 0; ni < 4; ++ni)
        acc[mi][ni] = __builtin_amdgcn_mfma_f32_16x16x32_bf16(af[mi], bfr[ni], acc[mi][ni], 0, 0, 0);
    __syncthreads();
  }

#pragma unroll
  for (int mi = 0; mi < 4; ++mi) {
#pragma unroll
    for (int ni = 0; ni < 4; ++ni) {
      const int col = bn + wn * 64 + ni * 16 + lrow;
      const float bv = (col < nsplit) ? bias0[col] : bias1[col - nsplit];
#pragma unroll
      for (int j = 0; j < 4; ++j) {
        const int row = bm + wm * 64 + mi * 16 + (lane >> 4) * 4 + j;   // m89-verified C/D map
        C[(size_t)row * N + col] = f2bf(acc[mi][ni][j] + bv);
      }
    }
  }
}

// ---------------- one LSTM timestep, both directions ----------------
// grid 32: dir = bid>>4, colgroup (32 hid cols) = bid&15. 256 threads (4 waves:
// mh=batch half, ch=col half). Each wave: 4 gates x (16 batch x 16 cols), K=512.
__global__ __launch_bounds__(256) void lstm_step(const unsigned short* __restrict__ Whh, // [2][2048][512] bf16
                                                 const unsigned short* __restrict__ xg,  // [4096][4096] bf16
                                                 unsigned short* __restrict__ hstate,    // [2buf][2dir][32][512] bf16
                                                 float* __restrict__ cstate,             // [2dir][32][512] f32
                                                 unsigned short* __restrict__ hseq,      // [128][32][1024] bf16
                                                 int s) {
  const int dir  = blockIdx.x >> 4;
  const int cg   = blockIdx.x & 15;
  const int t    = dir ? (127 - s) : s;
  const int lane = threadIdx.x & 63;
  const int wid  = threadIdx.x >> 6;
  const int mh   = wid & 1;
  const int ch   = wid >> 1;
  const int colbase = cg * 32 + ch * 16;
  const int lrow = lane & 15;
  const int lk   = (lane >> 4) * 8;

  const unsigned short* hprev = hstate + (size_t)(((s & 1) * 2 + dir) * 32) * 512;
  u16x8 afr[16];
#pragma unroll
  for (int kk = 0; kk < 16; ++kk)
    afr[kk] = *(const u16x8*)&hprev[(mh * 16 + lrow) * 512 + kk * 32 + lk];

  f32x4 acc[4];
#pragma unroll
  for (int g = 0; g < 4; ++g) acc[g] = (f32x4){0.f, 0.f, 0.f, 0.f};

#pragma unroll
  for (int g = 0; g < 4; ++g) {
    const unsigned short* wp = Whh + (size_t)(dir * 2048 + g * 512 + colbase + lrow) * 512 + lk;
#pragma unroll
    for (int kk = 0; kk < 16; ++kk) {
      u16x8 bq = *(const u16x8*)&wp[kk * 32];
      acc[g] = __builtin_amdgcn_mfma_f32_16x16x32_bf16(
          __builtin_bit_cast(bf16x8, afr[kk]), __builtin_bit_cast(bf16x8, bq), acc[g], 0, 0, 0);
    }
  }

  unsigned short* hnext = hstate + (size_t)((((s + 1) & 1) * 2 + dir) * 32) * 512;
  float* cst = cstate + (size_t)dir * 32 * 512;
  const int col = colbase + lrow;
#pragma unroll
  for (int j = 0; j < 4; ++j) {
    const int b = mh * 16 + (lane >> 4) * 4 + j;
    const size_t xrow = (size_t)(t * 32 + b) * 4096 + dir * 2048;   // bias already in xg
    float vi = acc[0][j] + bf2f(xg[xrow + 0 * 512 + col]);
    float vf = acc[1][j] + bf2f(xg[xrow + 1 * 512 + col]);
    float vg = acc[2][j] + bf2f(xg[xrow + 2 * 512 + col]);
    float vo = acc[3][j] + bf2f(xg[xrow + 3 * 512 + col]);
    float ig = 1.f / (1.f + expf(-vi));
    float fg = 1.f / (1.f + expf(-vf));
    float gv = tanhf(vg);
    float og = 1.f / (1.f + expf(-vo));
    float cn = fg * cst[b * 512 + col] + ig * gv;
    cst[b * 512 + col] = cn;
    float hv = og * tanhf(cn);
    unsigned short hb = f2bf(hv);
    hnext[b * 512 + col] = hb;
    hseq[(size_t)(t * 32 + b) * 1024 + dir * 512 + col] = hb;
  }
}

// ---------------- feats: [t*32+b][1024] bf16 @ W_lin^T(20,1024) + b_lin ----------------
// one wave per row; store feats[b][t][k]
__global__ __launch_bounds__(256) void feats_gemv(const unsigned short* __restrict__ hseq,
                                                  const float* __restrict__ Wlin,
                                                  const float* __restrict__ blin,
                                                  float* __restrict__ feats) {
  const int lane = threadIdx.x & 63;
  const int wid  = threadIdx.x >> 6;
  const int row  = blockIdx.x * 4 + wid;   // = t*32 + b
  const int t = row >> 5, b = row & 31;
  const unsigned short* hr = hseq + (size_t)row * 1024 + lane * 16;
  float hf[16];
  u16x8 h0 = *(const u16x8*)hr;
  u16x8 h1 = *(const u16x8*)(hr + 8);
#pragma unroll
  for (int i = 0; i < 8; ++i) { hf[i] = bf2f(h0[i]); hf[8 + i] = bf2f(h1[i]); }
  for (int k = 0; k < 20; ++k) {
    const float* wr = Wlin + k * 1024 + lane * 16;
    float p = 0.f;
#pragma unroll
    for (int q = 0; q < 4; ++q) {
      float4 w4 = ((const float4*)wr)[q];
      p += hf[q*4+0]*w4.x + hf[q*4+1]*w4.y + hf[q*4+2]*w4.z + hf[q*4+3]*w4.w;
    }
#pragma unroll
    for (int off = 32; off; off >>= 1) p += __shfl_xor(p, off);
    if (lane == 0) feats[(size_t)b * (128 * 20) + t * 20 + k] = p + blin[k];
  }
}

// ---------------- CRF NLL: one wave per batch ----------------
__global__ __launch_bounds__(64) void crf_nll(const float* __restrict__ feats, // [32][128][20]
                                              const int* __restrict__ tags,    // [32][128]
                                              const float* __restrict__ trans, // [20][20] row=next,col=prev
                                              float* __restrict__ out) {       // [32]
  const int b = blockIdx.x;
  const int j = threadIdx.x;      // lane: 0..19 = next-state, rest idle-safe
  const bool act = j < 20;
  float tr[20];
#pragma unroll
  for (int p = 0; p < 20; ++p) tr[p] = act ? trans[j * 20 + p] : 0.f;
  float alpha = (j == 18) ? 0.f : NEGV;   // START=18
  const float* fb = feats + (size_t)b * (128 * 20);
  for (int t = 0; t < 128; ++t) {
    float emit = act ? fb[t * 20 + j] : 0.f;
    float sc[20];
    float m = -1e30f;
#pragma unroll
    for (int p = 0; p < 20; ++p) {
      float ap = __shfl(alpha, p);
      sc[p] = ap + tr[p];
      m = fmaxf(m, sc[p]);
    }
    float sum = 0.f;
#pragma unroll
    for (int p = 0; p < 20; ++p) sum += expf(sc[p] - m);
    alpha = m + logf(sum) + emit;
  }
  // log_Z = logsumexp_j(alpha_j + trans[STOP][j])
  float v = act ? (alpha + trans[19 * 20 + j]) : -1e30f;
  float m2 = v;
#pragma unroll
  for (int off = 32; off; off >>= 1) m2 = fmaxf(m2, __shfl_xor(m2, off));
  float s2 = expf(v - m2);
#pragma unroll
  for (int off = 32; off; off >>= 1) s2 += __shfl_xor(s2, off);
  const float logZ = m2 + logf(s2);

  // gold score: trans over 129 transitions + emissions over 128 positions
  const int* tg = tags + b * 128;
  float ts;
  {
    int prev = (j == 0) ? 18 : tg[j - 1];
    ts = trans[tg[j] * 20 + prev];            // i = j
    ts += trans[tg[j + 64] * 20 + tg[j + 63]]; // i = j+64
    if (j == 0) ts += trans[19 * 20 + tg[127]]; // i = 128: STOP<-tags[127]
  }
  float es = fb[j * 20 + tg[j]] + fb[(j + 64) * 20 + tg[j + 64]];
  float tot = ts + es;
#pragma unroll
  for (int off = 32; off; off >>= 1) tot += __shfl_xor(tot, off);
  if (j == 0) out[b] = logZ - tot;
}

// ---------------- launch ----------------
extern "C" void kernel_launch(void* const* d_in, const int* in_sizes, int n_in,
                              void* d_out, int out_size, void* d_ws, size_t ws_size,
                              hipStream_t stream) {
  const float* x     = (const float*)d_in[0];
  const int*   tags  = (const int*)d_in[1];
  const float* We2n  = (const float*)d_in[2];
  const float* be2n  = (const float*)d_in[3];
  const float* Wihf  = (const float*)d_in[4];
  const float* Whhf  = (const float*)d_in[5];
  const float* bf_   = (const float*)d_in[6];
  const float* Wihb  = (const float*)d_in[7];
  const float* Whhb  = (const float*)d_in[8];
  const float* bb_   = (const float*)d_in[9];
  const float* Wlin  = (const float*)d_in[10];
  const float* blin  = (const float*)d_in[11];
  const float* trans = (const float*)d_in[12];

  char* ws = (char*)d_ws;
  // buffer reuse: buf0 = x_bf16 then xg; buf1 = W_e2n_bf16 then W_ih_bf16; buf2 = x'_bf16
  unsigned short* buf0   = (unsigned short*)(ws);
  unsigned short* buf1   = (unsigned short*)(ws + 33554432ULL);
  unsigned short* buf2   = (unsigned short*)(ws + 2ULL * 33554432ULL);
  unsigned short* whhb   = (unsigned short*)(ws + 3ULL * 33554432ULL);              // 4 MB
  unsigned short* hseq   = (unsigned short*)(ws + 3ULL * 33554432ULL + 4194304ULL); // 8 MB
  unsigned short* hstate = (unsigned short*)(ws + 3ULL * 33554432ULL + 12582912ULL); // 128 KB
  float*          cstate = (float*)(ws + 3ULL * 33554432ULL + 12713984ULL);          // 128 KB
  float*          feats  = (float*)(ws + 3ULL * 33554432ULL + 12845056ULL);          // 320 KB

  // 1. convert x, W_e2n, W_hh (bf16)
  cvt_f32_bf16<<<2048, 256, 0, stream>>>(x,    buf0, 16777216 / 4);
  cvt_f32_bf16<<<2048, 256, 0, stream>>>(We2n, buf1, 16777216 / 4);
  cvt_f32_bf16<<<512,  256, 0, stream>>>(Whhf, whhb,            1048576 / 4);
  cvt_f32_bf16<<<512,  256, 0, stream>>>(Whhb, whhb + 1048576,  1048576 / 4);
  hipMemsetAsync(hstate, 0, 262144, stream);  // h0 buffer + c state = 0

  // 2. x' = x @ W_e2n^T + b_e2n
  gemm_bf16<<<1024, 256, 0, stream>>>(buf0, buf1, buf2, be2n, be2n, 4096, 4096, 4096, 4096);

  // 3. W_ih_f/W_ih_b -> buf1 (W_e2n dead after GEMM1)
  cvt_f32_bf16<<<2048, 256, 0, stream>>>(Wihf, buf1,           8388608 / 4);
  cvt_f32_bf16<<<2048, 256, 0, stream>>>(Wihb, buf1 + 8388608, 8388608 / 4);

  // 4. xg = x' @ Wih^T + bias (forward cols 0..2047 -> b_f, backward -> b_b)
  gemm_bf16<<<1024, 256, 0, stream>>>(buf2, buf1, buf0, bf_, bb_, 2048, 4096, 4096, 4096);

  // 5. recurrence: 128 sequential step launches (stream order = coherence)
  for (int s = 0; s < 128; ++s)
    lstm_step<<<32, 256, 0, stream>>>(whhb, buf0, hstate, cstate, hseq, s);

  // 6. feats
  feats_gemv<<<1024, 256, 0, stream>>>(hseq, Wlin, blin, feats);

  // 7. CRF
  crf_nll<<<32, 64, 0, stream>>>(feats, tags, trans, (float*)d_out);
}

// Round 2
// 2188.316 us; speedup vs baseline: 1.1169x; 1.1169x over previous
//
#include <hip/hip_runtime.h>
#include <hip/hip_cooperative_groups.h>
#include <stdint.h>

// SequenceTagger: BiLSTM-CRF
//   T=128, B=32, E=4096, H=512, K=20, START=18, STOP=19, NEG=-1e4
// Pipeline:
//   1. cvt fp32->bf16: x, W_e2n, W_hh_f/b
//   2. GEMM1: x' = x @ W_e2n^T + b_e2n          (bf16 out)
//   3. cvt W_ih_f/b (reuse W_e2n buffer)
//   4. GEMM2: xg = x' @ [W_ih_f;W_ih_b]^T + b   (bf16 out, reuse x buffer)
//   5. persistent cooperative LSTM kernel (W_hh in LDS, c in registers,
//      grid.sync per step)
//   6. feats GEMV  7. CRF forward + score

#define NEGV (-10000.0f)

namespace cg = cooperative_groups;

typedef __bf16          bf16x8 __attribute__((ext_vector_type(8)));
typedef float           f32x4  __attribute__((ext_vector_type(4)));
typedef unsigned short  u16x8  __attribute__((ext_vector_type(8)));

typedef const __attribute__((address_space(1))) unsigned int* as1p;
typedef __attribute__((address_space(3))) unsigned int* as3p;

__device__ __forceinline__ void lds_cp16(const void* g, void* l) {
  __builtin_amdgcn_global_load_lds((as1p)g, (as3p)l, 16, 0, 0);
}

__device__ __forceinline__ unsigned short f2bf(float f) {
  unsigned int u = __float_as_uint(f);
  u += 0x7fffu + ((u >> 16) & 1u);   // RNE truncate to bf16
  return (unsigned short)(u >> 16);
}
__device__ __forceinline__ float bf2f(unsigned short h) {
  return __uint_as_float(((unsigned int)h) << 16);
}

// ---------------- fp32 -> bf16 (x4 vectorized) ----------------
__global__ __launch_bounds__(256) void cvt_f32_bf16(const float* __restrict__ in,
                                                    unsigned short* __restrict__ out,
                                                    int n4) {
  int stride = gridDim.x * blockDim.x;
  for (int i = blockIdx.x * blockDim.x + threadIdx.x; i < n4; i += stride) {
    float4 f = ((const float4*)in)[i];
    ushort4 o;
    o.x = f2bf(f.x); o.y = f2bf(f.y); o.z = f2bf(f.z); o.w = f2bf(f.w);
    ((ushort4*)out)[i] = o;
  }
}

// ---------------- bf16 GEMM: C[m,n] = sum_k A[m,k]*B[n,k] + bias(n) ----------------
// 128x128 tile, BK=32, 4 waves (2x2), each wave 64x64 via 4x4 MFMA 16x16x32.
__global__ __launch_bounds__(256) void gemm_bf16(const unsigned short* __restrict__ A,
                                                 const unsigned short* __restrict__ B,
                                                 unsigned short* __restrict__ C,
                                                 const float* __restrict__ bias0,
                                                 const float* __restrict__ bias1,
                                                 int nsplit, int M, int N, int K) {
  __shared__ unsigned short As[128 * 32];
  __shared__ unsigned short Bs[128 * 32];
  const int tid   = threadIdx.x;
  const int lane  = tid & 63;
  const int wm    = (tid >> 6) >> 1;
  const int wn    = (tid >> 6) & 1;
  const int nb    = N >> 7;
  const int bm    = (int)(blockIdx.x / nb) << 7;
  const int bn    = (int)(blockIdx.x % nb) << 7;
  const int srow  = tid >> 2;         // 0..63 staging row
  const int skoff = (tid & 3) * 8;    // 8-elem chunk in 32-elem row
  const int lrow  = lane & 15;
  const int lk    = (lane >> 4) * 8;

  f32x4 acc[4][4];
#pragma unroll
  for (int i = 0; i < 4; ++i)
#pragma unroll
    for (int j = 0; j < 4; ++j) acc[i][j] = (f32x4){0.f, 0.f, 0.f, 0.f};

  for (int k0 = 0; k0 < K; k0 += 32) {
    lds_cp16(A + (size_t)(bm + srow) * K + k0 + skoff,      &As[tid * 8]);
    lds_cp16(A + (size_t)(bm + 64 + srow) * K + k0 + skoff, &As[2048 + tid * 8]);
    lds_cp16(B + (size_t)(bn + srow) * K + k0 + skoff,      &Bs[tid * 8]);
    lds_cp16(B + (size_t)(bn + 64 + srow) * K + k0 + skoff, &Bs[2048 + tid * 8]);
    __syncthreads();
    bf16x8 af[4], bfr[4];
#pragma unroll
    for (int mi = 0; mi < 4; ++mi)
      af[mi] = *(const bf16x8*)&As[(wm * 64 + mi * 16 + lrow) * 32 + lk];
#pragma unroll
    for (int ni = 0; ni < 4; ++ni)
      bfr[ni] = *(const bf16x8*)&Bs[(wn * 64 + ni * 16 + lrow) * 32 + lk];
#pragma unroll
    for (int mi = 0; mi < 4; ++mi)
#pragma unroll
      for (int ni = 0; ni < 4; ++ni)
        acc[mi][ni] = __builtin_amdgcn_mfma_f32_16x16x32_bf16(af[mi], bfr[ni], acc[mi][ni], 0, 0, 0);
    __syncthreads();
  }

#pragma unroll
  for (int mi = 0; mi < 4; ++mi) {
#pragma unroll
    for (int ni = 0; ni < 4; ++ni) {
      const int col = bn + wn * 64 + ni * 16 + lrow;
      const float bv = (col < nsplit) ? bias0[col] : bias1[col - nsplit];
#pragma unroll
      for (int j = 0; j < 4; ++j) {
        const int row = bm + wm * 64 + mi * 16 + (lane >> 4) * 4 + j;
        C[(size_t)row * N + col] = f2bf(acc[mi][ni][j] + bv);
      }
    }
  }
}

// ---------------- persistent BiLSTM recurrence ----------------
// grid 32 (cooperative): dir = bid>>4, colgroup (32 hid cols) = bid&15.
// 512 threads = 8 waves: gate g = wid&3, batch-half mh = wid>>2.
// W_hh slice (4 gates x 32 cols x 512) staged once in LDS (rows padded to 520
// shorts -> bank stride 4 mod 32, conflict-free-ish ds_read_b128).
// Cell state lives in 2 registers per thread for all 128 steps.
// One grid.sync() per timestep; h double-buffered in global by step parity.
__global__ __launch_bounds__(512) void lstm_persist(const unsigned short* __restrict__ Whh, // [2][2048][512]
                                                    const unsigned short* __restrict__ xg,  // [4096][4096]
                                                    unsigned short* __restrict__ hstate,    // [2buf][2dir][32][512]
                                                    unsigned short* __restrict__ hseq) {    // [128][32][1024]
  __shared__ unsigned short Wlds[4 * 32 * 520];   // 133120 B
  __shared__ float G[4 * 32 * 36];                // 18432 B (padded: 36 f32/row)

  cg::grid_group grid = cg::this_grid();

  const int bid  = blockIdx.x;
  const int dir  = bid >> 4;
  const int cgc  = bid & 15;
  const int colbase = cgc * 32;
  const int tid  = threadIdx.x;
  const int lane = tid & 63;
  const int wid  = tid >> 6;
  const int g    = wid & 3;
  const int mh   = wid >> 2;
  const int lrow = lane & 15;
  const int lk4  = lane >> 4;
  const int lk   = lk4 * 8;

  // ---- stage W slice into LDS (once) ----
  for (int idx = tid; idx < 4 * 32 * 64; idx += 512) {
    const int g2 = idx >> 11;           // gate
    const int r  = (idx >> 6) & 31;     // col-row within slice
    const int c  = idx & 63;            // 8-short chunk
    u16x8 v = *(const u16x8*)&Whh[(size_t)(dir * 2048 + g2 * 512 + colbase + r) * 512 + c * 8];
    *(u16x8*)&Wlds[(g2 * 32 + r) * 520 + c * 8] = v;
  }
  __syncthreads();

  // elementwise ownership: thread handles idx0 = tid (b 0..15) and idx1 = tid+512 (b 16..31)
  const int b0  = tid >> 5,        col0 = tid & 31;
  const int b1  = (tid + 512) >> 5, col1 = tid & 31;
  float creg0 = 0.f, creg1 = 0.f;

  for (int s = 0; s < 128; ++s) {
    const int t = dir ? (127 - s) : s;

    // prefetch this step's xg values (independent of h -> overlaps MFMA phase)
    unsigned short xv0[4], xv1[4];
    {
      const size_t xr0 = (size_t)(t * 32 + b0) * 4096 + dir * 2048 + colbase + col0;
      const size_t xr1 = (size_t)(t * 32 + b1) * 4096 + dir * 2048 + colbase + col1;
#pragma unroll
      for (int g2 = 0; g2 < 4; ++g2) { xv0[g2] = xg[xr0 + g2 * 512]; xv1[g2] = xg[xr1 + g2 * 512]; }
    }

    // ---- MFMA phase: gate pre-activations (16 batch x 32 cols per wave) ----
    const unsigned short* hp = hstate + (size_t)((s & 1) * 2 + dir) * 32 * 512;
    u16x8 a[16];
#pragma unroll
    for (int kk = 0; kk < 16; ++kk)
      a[kk] = *(const u16x8*)&hp[(mh * 16 + lrow) * 512 + kk * 32 + lk];

    f32x4 acc[2] = {(f32x4){0.f,0.f,0.f,0.f}, (f32x4){0.f,0.f,0.f,0.f}};
#pragma unroll
    for (int ct = 0; ct < 2; ++ct)
#pragma unroll
      for (int kk = 0; kk < 16; ++kk) {
        u16x8 w = *(const u16x8*)&Wlds[(g * 32 + ct * 16 + lrow) * 520 + kk * 32 + lk];
        acc[ct] = __builtin_amdgcn_mfma_f32_16x16x32_bf16(
            __builtin_bit_cast(bf16x8, a[kk]), __builtin_bit_cast(bf16x8, w), acc[ct], 0, 0, 0);
      }

    // write gate pre-acts to LDS: G[g][b][col] (row padded to 36)
#pragma unroll
    for (int ct = 0; ct < 2; ++ct)
#pragma unroll
      for (int j = 0; j < 4; ++j)
        G[g * 1152 + (mh * 16 + lk4 * 4 + j) * 36 + ct * 16 + lrow] = acc[ct][j];
    __syncthreads();

    // ---- elementwise phase: cell update for 2 (b,col) pairs ----
    unsigned short* hn = hstate + (size_t)(((s + 1) & 1) * 2 + dir) * 32 * 512;
    {
      float vi = G[0 * 1152 + b0 * 36 + col0] + bf2f(xv0[0]);
      float vf = G[1 * 1152 + b0 * 36 + col0] + bf2f(xv0[1]);
      float vg = G[2 * 1152 + b0 * 36 + col0] + bf2f(xv0[2]);
      float vo = G[3 * 1152 + b0 * 36 + col0] + bf2f(xv0[3]);
      float ig = 1.f / (1.f + expf(-vi));
      float fg = 1.f / (1.f + expf(-vf));
      float gv = tanhf(vg);
      float og = 1.f / (1.f + expf(-vo));
      creg0 = fg * creg0 + ig * gv;
      unsigned short hb = f2bf(og * tanhf(creg0));
      hn[b0 * 512 + colbase + col0] = hb;
      hseq[(size_t)(t * 32 + b0) * 1024 + dir * 512 + colbase + col0] = hb;
    }
    {
      float vi = G[0 * 1152 + b1 * 36 + col1] + bf2f(xv1[0]);
      float vf = G[1 * 1152 + b1 * 36 + col1] + bf2f(xv1[1]);
      float vg = G[2 * 1152 + b1 * 36 + col1] + bf2f(xv1[2]);
      float vo = G[3 * 1152 + b1 * 36 + col1] + bf2f(xv1[3]);
      float ig = 1.f / (1.f + expf(-vi));
      float fg = 1.f / (1.f + expf(-vf));
      float gv = tanhf(vg);
      float og = 1.f / (1.f + expf(-vo));
      creg1 = fg * creg1 + ig * gv;
      unsigned short hb = f2bf(og * tanhf(creg1));
      hn[b1 * 512 + colbase + col1] = hb;
      hseq[(size_t)(t * 32 + b1) * 1024 + dir * 512 + colbase + col1] = hb;
    }

    grid.sync();   // h visible device-wide; also guards G reuse next step
  }
}

// ---------------- feats: [t*32+b][1024] bf16 @ W_lin^T(20,1024) + b_lin ----------------
__global__ __launch_bounds__(256) void feats_gemv(const unsigned short* __restrict__ hseq,
                                                  const float* __restrict__ Wlin,
                                                  const float* __restrict__ blin,
                                                  float* __restrict__ feats) {
  const int lane = threadIdx.x & 63;
  const int wid  = threadIdx.x >> 6;
  const int row  = blockIdx.x * 4 + wid;   // = t*32 + b
  const int t = row >> 5, b = row & 31;
  const unsigned short* hr = hseq + (size_t)row * 1024 + lane * 16;
  float hf[16];
  u16x8 h0 = *(const u16x8*)hr;
  u16x8 h1 = *(const u16x8*)(hr + 8);
#pragma unroll
  for (int i = 0; i < 8; ++i) { hf[i] = bf2f(h0[i]); hf[8 + i] = bf2f(h1[i]); }
  for (int k = 0; k < 20; ++k) {
    const float* wr = Wlin + k * 1024 + lane * 16;
    float p = 0.f;
#pragma unroll
    for (int q = 0; q < 4; ++q) {
      float4 w4 = ((const float4*)wr)[q];
      p += hf[q*4+0]*w4.x + hf[q*4+1]*w4.y + hf[q*4+2]*w4.z + hf[q*4+3]*w4.w;
    }
#pragma unroll
    for (int off = 32; off; off >>= 1) p += __shfl_xor(p, off);
    if (lane == 0) feats[(size_t)b * (128 * 20) + t * 20 + k] = p + blin[k];
  }
}

// ---------------- CRF NLL: one wave per batch ----------------
__global__ __launch_bounds__(64) void crf_nll(const float* __restrict__ feats, // [32][128][20]
                                              const int* __restrict__ tags,    // [32][128]
                                              const float* __restrict__ trans, // [20][20] row=next,col=prev
                                              float* __restrict__ out) {       // [32]
  const int b = blockIdx.x;
  const int j = threadIdx.x;
  const bool act = j < 20;
  float tr[20];
#pragma unroll
  for (int p = 0; p < 20; ++p) tr[p] = act ? trans[j * 20 + p] : 0.f;
  float alpha = (j == 18) ? 0.f : NEGV;   // START=18
  const float* fb = feats + (size_t)b * (128 * 20);
  for (int t = 0; t < 128; ++t) {
    float emit = act ? fb[t * 20 + j] : 0.f;
    float sc[20];
    float m = -1e30f;
#pragma unroll
    for (int p = 0; p < 20; ++p) {
      float ap = __shfl(alpha, p);
      sc[p] = ap + tr[p];
      m = fmaxf(m, sc[p]);
    }
    float sum = 0.f;
#pragma unroll
    for (int p = 0; p < 20; ++p) sum += expf(sc[p] - m);
    alpha = m + logf(sum) + emit;
  }
  float v = act ? (alpha + trans[19 * 20 + j]) : -1e30f;
  float m2 = v;
#pragma unroll
  for (int off = 32; off; off >>= 1) m2 = fmaxf(m2, __shfl_xor(m2, off));
  float s2 = expf(v - m2);
#pragma unroll
  for (int off = 32; off; off >>= 1) s2 += __shfl_xor(s2, off);
  const float logZ = m2 + logf(s2);

  const int* tg = tags + b * 128;
  float ts;
  {
    int prev = (j == 0) ? 18 : tg[j - 1];
    ts = trans[tg[j] * 20 + prev];
    ts += trans[tg[j + 64] * 20 + tg[j + 63]];
    if (j == 0) ts += trans[19 * 20 + tg[127]];
  }
  float es = fb[j * 20 + tg[j]] + fb[(j + 64) * 20 + tg[j + 64]];
  float tot = ts + es;
#pragma unroll
  for (int off = 32; off; off >>= 1) tot += __shfl_xor(tot, off);
  if (j == 0) out[b] = logZ - tot;
}

// ---------------- launch ----------------
extern "C" void kernel_launch(void* const* d_in, const int* in_sizes, int n_in,
                              void* d_out, int out_size, void* d_ws, size_t ws_size,
                              hipStream_t stream) {
  const float* x     = (const float*)d_in[0];
  const int*   tags  = (const int*)d_in[1];
  const float* We2n  = (const float*)d_in[2];
  const float* be2n  = (const float*)d_in[3];
  const float* Wihf  = (const float*)d_in[4];
  const float* Whhf  = (const float*)d_in[5];
  const float* bf_   = (const float*)d_in[6];
  const float* Wihb  = (const float*)d_in[7];
  const float* Whhb  = (const float*)d_in[8];
  const float* bb_   = (const float*)d_in[9];
  const float* Wlin  = (const float*)d_in[10];
  const float* blin  = (const float*)d_in[11];
  const float* trans = (const float*)d_in[12];

  char* ws = (char*)d_ws;
  unsigned short* buf0   = (unsigned short*)(ws);                                   // 32 MB
  unsigned short* buf1   = (unsigned short*)(ws + 33554432ULL);                     // 32 MB
  unsigned short* buf2   = (unsigned short*)(ws + 2ULL * 33554432ULL);              // 32 MB
  unsigned short* whhb   = (unsigned short*)(ws + 3ULL * 33554432ULL);              // 4 MB
  unsigned short* hseq   = (unsigned short*)(ws + 3ULL * 33554432ULL + 4194304ULL); // 8 MB
  unsigned short* hstate = (unsigned short*)(ws + 3ULL * 33554432ULL + 12582912ULL); // 128 KB
  float*          feats  = (float*)(ws + 3ULL * 33554432ULL + 12845056ULL);          // 320 KB

  // 1. convert x, W_e2n, W_hh (bf16)
  cvt_f32_bf16<<<2048, 256, 0, stream>>>(x,    buf0, 16777216 / 4);
  cvt_f32_bf16<<<2048, 256, 0, stream>>>(We2n, buf1, 16777216 / 4);
  cvt_f32_bf16<<<512,  256, 0, stream>>>(Whhf, whhb,            1048576 / 4);
  cvt_f32_bf16<<<512,  256, 0, stream>>>(Whhb, whhb + 1048576,  1048576 / 4);
  hipMemsetAsync(hstate, 0, 131072, stream);  // zero both h parity buffers

  // 2. x' = x @ W_e2n^T + b_e2n
  gemm_bf16<<<1024, 256, 0, stream>>>(buf0, buf1, buf2, be2n, be2n, 4096, 4096, 4096, 4096);

  // 3. W_ih_f/W_ih_b -> buf1 (W_e2n dead after GEMM1)
  cvt_f32_bf16<<<2048, 256, 0, stream>>>(Wihf, buf1,           8388608 / 4);
  cvt_f32_bf16<<<2048, 256, 0, stream>>>(Wihb, buf1 + 8388608, 8388608 / 4);

  // 4. xg = x' @ Wih^T + bias
  gemm_bf16<<<1024, 256, 0, stream>>>(buf2, buf1, buf0, bf_, bb_, 2048, 4096, 4096, 4096);

  // 5. persistent recurrence (cooperative: 32 blocks x 512 thr, 1 grid.sync/step)
  {
    void* args[] = { (void*)&whhb, (void*)&buf0, (void*)&hstate, (void*)&hseq };
    hipLaunchCooperativeKernel((void*)lstm_persist, dim3(32), dim3(512), args, 0, stream);
  }

  // 6. feats
  feats_gemv<<<1024, 256, 0, stream>>>(hseq, Wlin, blin, feats);

  // 7. CRF
  crf_nll<<<32, 64, 0, stream>>>(feats, tags, trans, (float*)d_out);
}